// Round 1
// baseline (32.463 us; speedup 1.0000x reference)
//
#include <hip/hip_runtime.h>
#include <math.h>

#define NODES   100000
#define DIM     128
#define NEDGES  1600000   // 4 * 400000

// Phase 1: per-node projections pu[n] = dot(h[n], Wu), pv[n] = dot(h[n], Wv).
// 32 lanes cooperate per node; each lane loads one float4 (16B) -> coalesced.
__global__ __launch_bounds__(256) void node_proj_kernel(
    const float* __restrict__ h,
    const float* __restrict__ W,      // 256 floats: Wu = W[0:128], Wv = W[128:256]
    float* __restrict__ pu,
    float* __restrict__ pv,
    int n_nodes)
{
    int tid  = blockIdx.x * blockDim.x + threadIdx.x;
    int lane = tid & 31;
    int node = tid >> 5;
    if (node >= n_nodes) return;

    const float4 hv = *reinterpret_cast<const float4*>(h + (size_t)node * DIM + lane * 4);
    const float4 wu = *reinterpret_cast<const float4*>(W + lane * 4);
    const float4 wv = *reinterpret_cast<const float4*>(W + DIM + lane * 4);

    float su = hv.x * wu.x + hv.y * wu.y + hv.z * wu.z + hv.w * wu.w;
    float sv = hv.x * wv.x + hv.y * wv.y + hv.z * wv.z + hv.w * wv.w;

    // Butterfly reduce across the 32-lane group (xor masks <= 16 stay in-group).
    #pragma unroll
    for (int off = 16; off >= 1; off >>= 1) {
        su += __shfl_xor(su, off);
        sv += __shfl_xor(sv, off);
    }

    if (lane == 0) {
        pu[node] = su;
        pv[node] = sv;
    }
}

// Phase 2: per-edge score. 4 edges per thread, vectorized index/output IO.
// pu/pv (800 KB total) are L2/L3-resident, so the 2 gathers per edge are cheap.
__global__ __launch_bounds__(256) void edge_score_kernel(
    const int*   __restrict__ src,
    const int*   __restrict__ dst,
    const float* __restrict__ pu,
    const float* __restrict__ pv,
    const float* __restrict__ bias_ptr,
    float* __restrict__ out,
    int n_quads)
{
    int i = blockIdx.x * blockDim.x + threadIdx.x;
    if (i >= n_quads) return;

    const float b = bias_ptr[0];

    int4 s4 = reinterpret_cast<const int4*>(src)[i];
    int4 d4 = reinterpret_cast<const int4*>(dst)[i];

    float4 r;
    r.x = pu[s4.x] + pv[d4.x] + b;
    r.y = pu[s4.y] + pv[d4.y] + b;
    r.z = pu[s4.z] + pv[d4.z] + b;
    r.w = pu[s4.w] + pv[d4.w] + b;

    r.x = 1.0f / (1.0f + expf(-r.x));
    r.y = 1.0f / (1.0f + expf(-r.y));
    r.z = 1.0f / (1.0f + expf(-r.z));
    r.w = 1.0f / (1.0f + expf(-r.w));

    reinterpret_cast<float4*>(out)[i] = r;
}

extern "C" void kernel_launch(void* const* d_in, const int* in_sizes, int n_in,
                              void* d_out, int out_size, void* d_ws, size_t ws_size,
                              hipStream_t stream) {
    const float* h    = (const float*)d_in[0];
    const int*   src  = (const int*)d_in[1];
    const int*   dst  = (const int*)d_in[2];
    const float* W    = (const float*)d_in[3];   // (1, 256)
    const float* bias = (const float*)d_in[4];   // (1,)
    float* out = (float*)d_out;

    float* pu = (float*)d_ws;                    // NODES floats
    float* pv = pu + NODES;                      // NODES floats

    // Phase 1: 32 lanes/node -> NODES*32 threads.
    {
        int threads = 256;
        int total   = NODES * 32;
        int blocks  = (total + threads - 1) / threads;
        node_proj_kernel<<<blocks, threads, 0, stream>>>(h, W, pu, pv, NODES);
    }

    // Phase 2: 4 edges/thread.
    {
        int threads = 256;
        int n_quads = NEDGES / 4;
        int blocks  = (n_quads + threads - 1) / threads;
        edge_score_kernel<<<blocks, threads, 0, stream>>>(src, dst, pu, pv, bias, out, n_quads);
    }
}